// Round 3
// baseline (301.129 us; speedup 1.0000x reference)
//
#include <hip/hip_runtime.h>
#include <cstdint>
#include <cstddef>

// ---------------------------------------------------------------------------
// ThalamicRNN step. Inputs/outputs are FP32 (per reference); internal GEMM is
// bf16 MFMA with fp32 accumulation (harness threshold 5.8e-2 permits this).
//   A' = [ r | stim | t ]           (2048 x 2240) bf16, t = tha * (r @ V^T)
//   B' = [ J^T | I_stim^T | U ]     (2048 x 2240) bf16
//   acc = A' @ B'^T                 (2048 x 2048) fp32
//   x_new = x + (DT/TAU)*(-x + acc + B + SIGMA*eps);  r_new = softplus(x_new)
// ---------------------------------------------------------------------------

#define K_TOT 2240   // 2048 (J) + 128 (I_stim) + 64 (U)
#define NN    2048   // N == BATCH == 2048

using frag_ab = __attribute__((ext_vector_type(8))) short;   // 8 bf16
using frag_cd = __attribute__((ext_vector_type(4))) float;   // 4 fp32

__device__ __forceinline__ unsigned short f2bf(float f) {
  union { float f; unsigned int i; } v;
  v.f = f;
  unsigned int r = v.i + 0x7fffu + ((v.i >> 16) & 1u);  // RNE
  return (unsigned short)(r >> 16);
}

// load 8 consecutive floats, convert to 8 bf16 packed in a uint4
__device__ __forceinline__ uint4 cvt8(const float* __restrict__ p) {
  float4 a = *(const float4*)p;
  float4 b = *(const float4*)(p + 4);
  union { uint4 v; unsigned short u[8]; } d;
  d.u[0] = f2bf(a.x); d.u[1] = f2bf(a.y); d.u[2] = f2bf(a.z); d.u[3] = f2bf(a.w);
  d.u[4] = f2bf(b.x); d.u[5] = f2bf(b.y); d.u[6] = f2bf(b.z); d.u[7] = f2bf(b.w);
  return d.v;
}

// ---------------------------------------------------------------------------
// 64x64 LDS-tiled transpose + fp32->bf16: dst[col][dst_off+row] = bf16(src[row][col])
// src is R x srcC row-major fp32; dst row stride K_TOT (bf16).
// ---------------------------------------------------------------------------
__global__ __launch_bounds__(256) void transpose_pack(
    const float* __restrict__ src, unsigned short* __restrict__ dst,
    int srcC, int dst_off) {
  __shared__ unsigned short tile[64 * 66];  // +2 stride breaks bank collapse
  const int t  = threadIdx.x;
  const int r0 = blockIdx.y * 64;
  const int c0 = blockIdx.x * 64;
  const int sr = t >> 3, c8 = t & 7;
#pragma unroll
  for (int p = 0; p < 2; ++p) {
    const int row = sr + 32 * p;
    union { uint4 v; unsigned short u[8]; } d;
    d.v = cvt8(&src[(size_t)(r0 + row) * srcC + c0 + c8 * 8]);
#pragma unroll
    for (int e = 0; e < 8; ++e) tile[row * 66 + c8 * 8 + e] = d.u[e];
  }
  __syncthreads();
#pragma unroll
  for (int p = 0; p < 2; ++p) {
    const int scol = sr + 32 * p;  // src col == dst row within tile
    union { uint4 v; unsigned short u[8]; } d;
#pragma unroll
    for (int e = 0; e < 8; ++e) d.u[e] = tile[(c8 * 8 + e) * 66 + scol];
    *(uint4*)&dst[(size_t)(c0 + scol) * K_TOT + dst_off + r0 + c8 * 8] = d.v;
  }
}

// ---------------------------------------------------------------------------
// Pack r, stim (fp32->bf16) into A' cols [0,2176); U into B' cols [2176,2240).
// ---------------------------------------------------------------------------
__global__ __launch_bounds__(256) void pack_misc(
    const float* __restrict__ rg, const float* __restrict__ stim,
    const float* __restrict__ U, unsigned short* __restrict__ Ap,
    unsigned short* __restrict__ Bp) {
  const int row = blockIdx.x;
  const int t = threadIdx.x;
  *(uint4*)&Ap[(size_t)row * K_TOT + t * 8] = cvt8(&rg[(size_t)row * 2048 + t * 8]);
  if (t < 24) {
    const int c = 256 + t;
    if (c < 272) {
      *(uint4*)&Ap[(size_t)row * K_TOT + c * 8] =
          cvt8(&stim[(size_t)row * 128 + (c - 256) * 8]);
    } else {
      *(uint4*)&Bp[(size_t)row * K_TOT + c * 8] =
          cvt8(&U[(size_t)row * 64 + (c - 272) * 8]);
    }
  }
}

// ---------------------------------------------------------------------------
// t[b,p] = tha[b,p] * sum_k r[b,k] * V[p,k]  -> bf16 into A'[b][2176+p]
// BM=32, BN=64(=RANK), BK=64; 64 blocks x 256 threads (4 waves).
// ---------------------------------------------------------------------------
__global__ __launch_bounds__(256) void t_gemm(
    const float* __restrict__ rg, const float* __restrict__ V,
    const float* __restrict__ tha, unsigned short* __restrict__ Ap) {
  __shared__ alignas(16) unsigned short Ats[32 * 64];
  __shared__ alignas(16) unsigned short Bts[64 * 64];
  const int t = threadIdx.x;
  const int wave = t >> 6, lane = t & 63;
  const int q = lane >> 4, l15 = lane & 15;
  const int b0 = blockIdx.x * 32;
  const int arow = t >> 3, ac8 = t & 7;

  const float* gA  = rg + (size_t)(b0 + arow) * 2048 + ac8 * 8;
  const float* gB0 = V  + (size_t)arow        * 2048 + ac8 * 8;
  const float* gB1 = V  + (size_t)(arow + 32) * 2048 + ac8 * 8;

  frag_cd acc0 = {0.f, 0.f, 0.f, 0.f};
  frag_cd acc1 = {0.f, 0.f, 0.f, 0.f};

  for (int kt = 0; kt < 32; ++kt) {
    const int k0 = kt * 64;
    uint4 va  = cvt8(gA + k0);
    uint4 vb0 = cvt8(gB0 + k0);
    uint4 vb1 = cvt8(gB1 + k0);
    __syncthreads();
    *(uint4*)&Ats[t * 8]        = va;   // Ats[row*64 + c8*8] = A[b0+row][k-chunk]
    *(uint4*)&Bts[t * 8]        = vb0;  // V rows 0..31
    *(uint4*)&Bts[2048 + t * 8] = vb1;  // V rows 32..63
    __syncthreads();
#pragma unroll
    for (int ks = 0; ks < 2; ++ks) {
      frag_ab a0 = *(const frag_ab*)&Ats[(l15)      * 64 + ks * 32 + q * 8];
      frag_ab a1 = *(const frag_ab*)&Ats[(16 + l15) * 64 + ks * 32 + q * 8];
      frag_ab b  = *(const frag_ab*)&Bts[(wave * 16 + l15) * 64 + ks * 32 + q * 8];
      acc0 = __builtin_amdgcn_mfma_f32_16x16x32_bf16(a0, b, acc0, 0, 0, 0);
      acc1 = __builtin_amdgcn_mfma_f32_16x16x32_bf16(a1, b, acc1, 0, 0, 0);
    }
  }
  const int p = wave * 16 + l15;
#pragma unroll
  for (int reg = 0; reg < 4; ++reg) {
    int b = b0 + q * 4 + reg;   // C/D: row = quad*4 + reg, col = lane&15
    Ap[(size_t)b * K_TOT + 2176 + p] = f2bf(tha[(size_t)b * 64 + p] * acc0[reg]);
    b += 16;
    Ap[(size_t)b * K_TOT + 2176 + p] = f2bf(tha[(size_t)b * 64 + p] * acc1[reg]);
  }
}

// ---------------------------------------------------------------------------
// Main fused GEMM + epilogue. C = A'(2048x2240) @ B'^T(2048x2240), fp32 out.
// 128x128 tile, BK=64, 256 threads (4 waves, 64x64 quadrant each, 4x4 acc).
// bf16 LDS staging with 16B-chunk XOR swizzle; epilogue fp32 direct from acc.
// ---------------------------------------------------------------------------
__global__ __launch_bounds__(256, 2) void main_gemm(
    const unsigned short* __restrict__ Ap, const unsigned short* __restrict__ Bp,
    const float* __restrict__ xg, const float* __restrict__ epsg,
    const float* __restrict__ Bvec,
    float* __restrict__ outx, float* __restrict__ outr) {
  __shared__ alignas(16) unsigned short smem[16384];  // As[8192] | Bs[8192]
  unsigned short* As = smem;
  unsigned short* Bs = smem + 8192;

  const int t = threadIdx.x;
  const int wave = t >> 6, lane = t & 63;
  const int q = lane >> 4, l15 = lane & 15, l7 = lane & 7;
  const int mw = (wave & 1) * 64, nw = (wave >> 1) * 64;
  const int bm0 = blockIdx.y * 128, bn0 = blockIdx.x * 128;

  // staging: thread t, slice r -> slot ci = r*256+t holds row=ci>>3,
  // physical chunk ci&7 = logical chunk (ci&7)^(row&7)  (XOR swizzle, 16B units)
  const unsigned short* gA[4];
  const unsigned short* gB[4];
  int lslot[4];
#pragma unroll
  for (int r = 0; r < 4; ++r) {
    const int ci = r * 256 + t;
    const int row = ci >> 3;
    const int lc = (ci & 7) ^ (row & 7);
    gA[r] = Ap + (size_t)(bm0 + row) * K_TOT + lc * 8;
    gB[r] = Bp + (size_t)(bn0 + row) * K_TOT + lc * 8;
    lslot[r] = ci * 8;
  }

  frag_cd acc[4][4];
#pragma unroll
  for (int i = 0; i < 4; ++i)
#pragma unroll
    for (int j = 0; j < 4; ++j) {
      frag_cd z = {0.f, 0.f, 0.f, 0.f};
      acc[i][j] = z;
    }

  for (int kt = 0; kt < 35; ++kt) {  // 35 * 64 == 2240
    const int k0 = kt * 64;
    uint4 va[4], vb[4];
#pragma unroll
    for (int r = 0; r < 4; ++r) {
      va[r] = *(const uint4*)(gA[r] + k0);
      vb[r] = *(const uint4*)(gB[r] + k0);
    }
    __syncthreads();
#pragma unroll
    for (int r = 0; r < 4; ++r) {
      *(uint4*)&As[lslot[r]] = va[r];
      *(uint4*)&Bs[lslot[r]] = vb[r];
    }
    __syncthreads();
#pragma unroll
    for (int ks = 0; ks < 2; ++ks) {
      frag_ab af[4], bfr[4];
      const int lc = ks * 4 + q;   // logical chunk; phys = lc ^ (row&7)
#pragma unroll
      for (int i = 0; i < 4; ++i) {
        const int ra = mw + i * 16 + l15;
        af[i] = *(const frag_ab*)&As[ra * 64 + ((lc ^ l7) * 8)];
        const int rb = nw + i * 16 + l15;
        bfr[i] = *(const frag_ab*)&Bs[rb * 64 + ((lc ^ l7) * 8)];
      }
#pragma unroll
      for (int i = 0; i < 4; ++i)
#pragma unroll
        for (int j = 0; j < 4; ++j)
          acc[i][j] = __builtin_amdgcn_mfma_f32_16x16x32_bf16(af[i], bfr[j], acc[i][j], 0, 0, 0);
    }
  }

  // ---- epilogue: fp32, direct from accumulator C-layout ------------------
  const float A_DT = 0.33333334f;          // DT/TAU
  const float SIG  = 0.81649658092772615f; // sqrt(2*DT/TAU)
#pragma unroll
  for (int j = 0; j < 4; ++j) {
    const int nc = bn0 + nw + j * 16 + l15;    // C/D col = lane&15
    const float bvf = Bvec[nc];
#pragma unroll
    for (int i = 0; i < 4; ++i) {
#pragma unroll
      for (int reg = 0; reg < 4; ++reg) {
        const int mr = bm0 + mw + i * 16 + q * 4 + reg;  // C/D row = quad*4+reg
        const size_t off = (size_t)mr * NN + nc;
        const float xf = xg[off];
        const float ef = epsg[off];
        const float xn = xf + A_DT * (acc[i][j][reg] + bvf - xf + SIG * ef);
        outx[off] = xn;
        outr[off] = (xn > 20.f) ? xn : log1pf(__expf(xn));
      }
    }
  }
}

// ---------------------------------------------------------------------------
extern "C" void kernel_launch(void* const* d_in, const int* in_sizes, int n_in,
                              void* d_out, int out_size, void* d_ws, size_t ws_size,
                              hipStream_t stream) {
  (void)in_sizes; (void)n_in; (void)out_size; (void)ws_size;
  const float* tha  = (const float*)d_in[0];  // (2048,64)
  const float* stim = (const float*)d_in[1];  // (2048,128)
  const float* x    = (const float*)d_in[2];  // (2048,2048)
  const float* r    = (const float*)d_in[3];  // (2048,2048)
  const float* J    = (const float*)d_in[4];  // (2048,2048)
  const float* Bv   = (const float*)d_in[5];  // (1,2048)
  const float* U    = (const float*)d_in[6];  // (2048,64)
  const float* V    = (const float*)d_in[7];  // (64,2048)
  const float* Ist  = (const float*)d_in[8];  // (128,2048)
  const float* eps  = (const float*)d_in[9];  // (2048,2048)

  unsigned short* Apk = (unsigned short*)d_ws;            // 2048*2240 bf16
  unsigned short* Bpk = Apk + (size_t)NN * K_TOT;         // 2048*2240 bf16
  float* outx = (float*)d_out;
  float* outr = outx + (size_t)NN * NN;

  transpose_pack<<<dim3(32, 32), 256, 0, stream>>>(J, Bpk, 2048, 0);
  transpose_pack<<<dim3(32, 2), 256, 0, stream>>>(Ist, Bpk, 2048, 2048);
  pack_misc<<<2048, 256, 0, stream>>>(r, stim, U, Apk, Bpk);
  t_gemm<<<64, 256, 0, stream>>>(r, V, tha, Apk);
  main_gemm<<<dim3(16, 16), 256, 0, stream>>>(Apk, Bpk, x, eps, Bv, outx, outr);
}

// Round 4
// 186.187 us; speedup vs baseline: 1.6173x; 1.6173x over previous
//
#include <hip/hip_runtime.h>
#include <cstdint>
#include <cstddef>

// ---------------------------------------------------------------------------
// ThalamicRNN step. FP32 in/out; internal GEMM bf16 MFMA + fp32 accum.
//   A' = [ r | stim | t ]           (2048 x 2240) bf16, t = tha * (r @ V^T)
//   B' = [ J^T | I_stim^T | U ]     (2048 x 2240) bf16
//   acc = A' @ B'^T; x_new = x + (DT/TAU)*(-x+acc+B+SIG*eps); r_new = softplus
// Round 4: async global_load_lds staging, 64x128 main tiles (512 blocks,
// 2/CU), split-K t-path, fused prep kernel.
// ---------------------------------------------------------------------------

#define K_TOT 2240
#define NN    2048

using frag_ab = __attribute__((ext_vector_type(8))) short;   // 8 bf16
using frag_cd = __attribute__((ext_vector_type(4))) float;   // 4 fp32

__device__ __forceinline__ unsigned short f2bf(float f) {
  union { float f; unsigned int i; } v;
  v.f = f;
  unsigned int r = v.i + 0x7fffu + ((v.i >> 16) & 1u);  // RNE
  return (unsigned short)(r >> 16);
}

__device__ __forceinline__ uint4 cvt8(const float* __restrict__ p) {
  float4 a = *(const float4*)p;
  float4 b = *(const float4*)(p + 4);
  union { uint4 v; unsigned short u[8]; } d;
  d.u[0] = f2bf(a.x); d.u[1] = f2bf(a.y); d.u[2] = f2bf(a.z); d.u[3] = f2bf(a.w);
  d.u[4] = f2bf(b.x); d.u[5] = f2bf(b.y); d.u[6] = f2bf(b.z); d.u[7] = f2bf(b.w);
  return d.v;
}

// async global->LDS, 16 B/lane; LDS dest = wave-uniform base + lane*16.
__device__ __forceinline__ void gl_lds16(const void* g, void* l) {
  __builtin_amdgcn_global_load_lds(
      (const __attribute__((address_space(1))) void*)g,
      (__attribute__((address_space(3))) void*)l, 16, 0, 0);
}

// ---------------------------------------------------------------------------
// prep: fused  J-transpose (blocks [0,1024))  +  I_stim-transpose ([1024,1088))
//              +  r/stim/U packing ([1088,3136)).
// ---------------------------------------------------------------------------
__global__ __launch_bounds__(256) void prep(
    const float* __restrict__ J, const float* __restrict__ Ist,
    const float* __restrict__ rg, const float* __restrict__ stim,
    const float* __restrict__ U, unsigned short* __restrict__ Ap,
    unsigned short* __restrict__ Bp) {
  __shared__ unsigned short tile[64 * 66];
  const int blk = blockIdx.x;
  const int t = threadIdx.x;
  if (blk < 1088) {
    const float* src;
    int srcC = 2048, dst_off, cx, cy;
    if (blk < 1024) { src = J;   dst_off = 0;    cx = blk & 31; cy = blk >> 5; }
    else            { src = Ist; dst_off = 2048; cx = (blk - 1024) & 31; cy = (blk - 1024) >> 5; }
    const int r0 = cy * 64, c0 = cx * 64;
    const int sr = t >> 3, c8 = t & 7;
#pragma unroll
    for (int p = 0; p < 2; ++p) {
      const int row = sr + 32 * p;
      union { uint4 v; unsigned short u[8]; } d;
      d.v = cvt8(&src[(size_t)(r0 + row) * srcC + c0 + c8 * 8]);
#pragma unroll
      for (int e = 0; e < 8; ++e) tile[row * 66 + c8 * 8 + e] = d.u[e];
    }
    __syncthreads();
#pragma unroll
    for (int p = 0; p < 2; ++p) {
      const int scol = sr + 32 * p;
      union { uint4 v; unsigned short u[8]; } d;
#pragma unroll
      for (int e = 0; e < 8; ++e) d.u[e] = tile[(c8 * 8 + e) * 66 + scol];
      *(uint4*)&Bp[(size_t)(c0 + scol) * K_TOT + dst_off + r0 + c8 * 8] = d.v;
    }
  } else {
    const int row = blk - 1088;
    *(uint4*)&Ap[(size_t)row * K_TOT + t * 8] = cvt8(&rg[(size_t)row * 2048 + t * 8]);
    if (t < 24) {
      const int c = 256 + t;
      if (c < 272)
        *(uint4*)&Ap[(size_t)row * K_TOT + c * 8] =
            cvt8(&stim[(size_t)row * 128 + (c - 256) * 8]);
      else
        *(uint4*)&Bp[(size_t)row * K_TOT + c * 8] =
            cvt8(&U[(size_t)row * 64 + (c - 272) * 8]);
    }
  }
}

// ---------------------------------------------------------------------------
// t_part: partial t GEMM. grid 256 = 64 m-tiles (32 rows) x 4 k-slices (512).
// part[s][b][p] = sum_{k in slice s} r[b,k]*V[p,k]   (fp32, scratch)
// ---------------------------------------------------------------------------
__global__ __launch_bounds__(256) void t_part(
    const float* __restrict__ rg, const float* __restrict__ V,
    float* __restrict__ part) {
  __shared__ alignas(16) unsigned short Ats[32 * 64];
  __shared__ alignas(16) unsigned short Bts[64 * 64];
  const int t = threadIdx.x;
  const int wave = t >> 6, lane = t & 63;
  const int q = lane >> 4, l15 = lane & 15;
  const int mt = blockIdx.x & 63, s = blockIdx.x >> 6;
  const int b0 = mt * 32;
  const int arow = t >> 3, ac8 = t & 7;

  const float* gA  = rg + (size_t)(b0 + arow) * 2048 + s * 512 + ac8 * 8;
  const float* gB0 = V  + (size_t)arow        * 2048 + s * 512 + ac8 * 8;
  const float* gB1 = V  + (size_t)(arow + 32) * 2048 + s * 512 + ac8 * 8;

  frag_cd acc0 = {0.f, 0.f, 0.f, 0.f};
  frag_cd acc1 = {0.f, 0.f, 0.f, 0.f};

  for (int kt = 0; kt < 8; ++kt) {
    const int k0 = kt * 64;
    uint4 va  = cvt8(gA + k0);
    uint4 vb0 = cvt8(gB0 + k0);
    uint4 vb1 = cvt8(gB1 + k0);
    __syncthreads();
    *(uint4*)&Ats[t * 8]        = va;
    *(uint4*)&Bts[t * 8]        = vb0;
    *(uint4*)&Bts[2048 + t * 8] = vb1;
    __syncthreads();
#pragma unroll
    for (int ks = 0; ks < 2; ++ks) {
      frag_ab a0 = *(const frag_ab*)&Ats[(l15)      * 64 + ks * 32 + q * 8];
      frag_ab a1 = *(const frag_ab*)&Ats[(16 + l15) * 64 + ks * 32 + q * 8];
      frag_ab b  = *(const frag_ab*)&Bts[(wave * 16 + l15) * 64 + ks * 32 + q * 8];
      acc0 = __builtin_amdgcn_mfma_f32_16x16x32_bf16(a0, b, acc0, 0, 0, 0);
      acc1 = __builtin_amdgcn_mfma_f32_16x16x32_bf16(a1, b, acc1, 0, 0, 0);
    }
  }
  const int p = wave * 16 + l15;
#pragma unroll
  for (int reg = 0; reg < 4; ++reg) {
    const int m0 = q * 4 + reg;   // C/D: row = quad*4+reg, col = lane&15
    part[((size_t)s * 2048 + b0 + m0) * 64 + p]      = acc0[reg];
    part[((size_t)s * 2048 + b0 + m0 + 16) * 64 + p] = acc1[reg];
  }
}

// ---------------------------------------------------------------------------
// t_reduce: t[b,p] = tha[b,p] * sum_s part[s][b][p]  -> bf16 A'[b][2176+p]
// 128 blocks x 256 threads x 4 elems (float4).
// ---------------------------------------------------------------------------
__global__ __launch_bounds__(256) void t_reduce(
    const float* __restrict__ part, const float* __restrict__ tha,
    unsigned short* __restrict__ Ap) {
  const int e = blockIdx.x * 256 + threadIdx.x;   // float4 index, 0..32767
  float4 s0 = *(const float4*)(part + (size_t)e * 4);
  float4 s1 = *(const float4*)(part + 131072 + (size_t)e * 4);
  float4 s2 = *(const float4*)(part + 262144 + (size_t)e * 4);
  float4 s3 = *(const float4*)(part + 393216 + (size_t)e * 4);
  float4 th = *(const float4*)(tha + (size_t)e * 4);
  union { uint2 v; unsigned short u[4]; } o;
  o.u[0] = f2bf(th.x * (s0.x + s1.x + s2.x + s3.x));
  o.u[1] = f2bf(th.y * (s0.y + s1.y + s2.y + s3.y));
  o.u[2] = f2bf(th.z * (s0.z + s1.z + s2.z + s3.z));
  o.u[3] = f2bf(th.w * (s0.w + s1.w + s2.w + s3.w));
  const int b = e >> 4, p0 = (e * 4) & 63;
  *(uint2*)&Ap[(size_t)b * K_TOT + 2176 + p0] = o.v;
}

// ---------------------------------------------------------------------------
// Main GEMM + epilogue. 64x128 (MxN) tile, BK=64, 256 threads (4 waves, each
// 32x64, acc[2][4]). Async global_load_lds staging; XOR-swizzled LDS; fp32
// epilogue direct from accumulators.
// ---------------------------------------------------------------------------
__global__ __launch_bounds__(256, 2) void main_gemm(
    const unsigned short* __restrict__ Ap, const unsigned short* __restrict__ Bp,
    const float* __restrict__ xg, const float* __restrict__ epsg,
    const float* __restrict__ Bvec,
    float* __restrict__ outx, float* __restrict__ outr) {
  __shared__ alignas(16) unsigned short As[64 * 64];    // 8 KB
  __shared__ alignas(16) unsigned short Bs[128 * 64];   // 16 KB

  const int t = threadIdx.x;
  const int wave = t >> 6, lane = t & 63;
  const int q = lane >> 4, l15 = lane & 15, l7 = lane & 7;
  const int wm = (wave & 1) * 32, wn = (wave >> 1) * 64;
  const int bm0 = blockIdx.y * 64, bn0 = blockIdx.x * 128;

  // staging: slot ci (16B units) holds row=ci>>3, logical chunk (ci&7)^(row&7)
  const unsigned short* gA[2];
  unsigned short* lA[2];
  const unsigned short* gB[4];
  unsigned short* lB[4];
#pragma unroll
  for (int r = 0; r < 2; ++r) {
    const int ci = r * 256 + t;
    const int row = ci >> 3;
    const int lc = (ci & 7) ^ (row & 7);
    gA[r] = Ap + (size_t)(bm0 + row) * K_TOT + lc * 8;
    lA[r] = As + (size_t)(r * 256 + wave * 64) * 8;   // wave-uniform base
  }
#pragma unroll
  for (int r = 0; r < 4; ++r) {
    const int ci = r * 256 + t;
    const int row = ci >> 3;
    const int lc = (ci & 7) ^ (row & 7);
    gB[r] = Bp + (size_t)(bn0 + row) * K_TOT + lc * 8;
    lB[r] = Bs + (size_t)(r * 256 + wave * 64) * 8;
  }

  frag_cd acc[2][4];
#pragma unroll
  for (int i = 0; i < 2; ++i)
#pragma unroll
    for (int j = 0; j < 4; ++j) {
      frag_cd z = {0.f, 0.f, 0.f, 0.f};
      acc[i][j] = z;
    }

  for (int kt = 0; kt < 35; ++kt) {  // 35 * 64 == 2240
    const int k0 = kt * 64;
    __syncthreads();
#pragma unroll
    for (int r = 0; r < 2; ++r) gl_lds16(gA[r] + k0, lA[r]);
#pragma unroll
    for (int r = 0; r < 4; ++r) gl_lds16(gB[r] + k0, lB[r]);
    __syncthreads();
#pragma unroll
    for (int ks = 0; ks < 2; ++ks) {
      const int lc = ks * 4 + q;
      frag_ab af[2], bfr[4];
#pragma unroll
      for (int i = 0; i < 2; ++i) {
        const int ra = wm + i * 16 + l15;
        af[i] = *(const frag_ab*)&As[ra * 64 + ((lc ^ l7) * 8)];
      }
#pragma unroll
      for (int j = 0; j < 4; ++j) {
        const int rb = wn + j * 16 + l15;
        bfr[j] = *(const frag_ab*)&Bs[rb * 64 + ((lc ^ l7) * 8)];
      }
#pragma unroll
      for (int i = 0; i < 2; ++i)
#pragma unroll
        for (int j = 0; j < 4; ++j)
          acc[i][j] = __builtin_amdgcn_mfma_f32_16x16x32_bf16(af[i], bfr[j], acc[i][j], 0, 0, 0);
    }
  }

  // ---- epilogue: fp32 direct from accumulator C-layout -------------------
  const float A_DT = 0.33333334f;          // DT/TAU
  const float SIG  = 0.81649658092772615f; // sqrt(2*DT/TAU)
#pragma unroll
  for (int j = 0; j < 4; ++j) {
    const int nc = bn0 + wn + j * 16 + l15;    // C/D col = lane&15
    const float bvf = Bvec[nc];
#pragma unroll
    for (int i = 0; i < 2; ++i) {
#pragma unroll
      for (int reg = 0; reg < 4; ++reg) {
        const int mr = bm0 + wm + i * 16 + q * 4 + reg;  // C/D row = quad*4+reg
        const size_t off = (size_t)mr * NN + nc;
        const float xf = xg[off];
        const float ef = epsg[off];
        const float xn = xf + A_DT * (acc[i][j][reg] + bvf - xf + SIG * ef);
        outx[off] = xn;
        outr[off] = (xn > 20.f) ? xn : log1pf(__expf(xn));
      }
    }
  }
}

// ---------------------------------------------------------------------------
extern "C" void kernel_launch(void* const* d_in, const int* in_sizes, int n_in,
                              void* d_out, int out_size, void* d_ws, size_t ws_size,
                              hipStream_t stream) {
  (void)in_sizes; (void)n_in; (void)out_size; (void)ws_size;
  const float* tha  = (const float*)d_in[0];  // (2048,64)
  const float* stim = (const float*)d_in[1];  // (2048,128)
  const float* x    = (const float*)d_in[2];  // (2048,2048)
  const float* r    = (const float*)d_in[3];  // (2048,2048)
  const float* J    = (const float*)d_in[4];  // (2048,2048)
  const float* Bv   = (const float*)d_in[5];  // (1,2048)
  const float* U    = (const float*)d_in[6];  // (2048,64)
  const float* V    = (const float*)d_in[7];  // (64,2048)
  const float* Ist  = (const float*)d_in[8];  // (128,2048)
  const float* eps  = (const float*)d_in[9];  // (2048,2048)

  unsigned short* Apk = (unsigned short*)d_ws;            // 2048*2240 bf16
  unsigned short* Bpk = Apk + (size_t)NN * K_TOT;         // 2048*2240 bf16
  float* outx = (float*)d_out;
  float* outr = outx + (size_t)NN * NN;
  // t-partials scratch: reuse d_out (2 MB of 32 MB; overwritten by main_gemm)
  float* tpart = (float*)d_out;

  prep<<<3136, 256, 0, stream>>>(J, Ist, r, stim, U, Apk, Bpk);
  t_part<<<256, 256, 0, stream>>>(r, V, tpart);
  t_reduce<<<128, 256, 0, stream>>>(tpart, tha, Apk);
  main_gemm<<<dim3(16, 32), 256, 0, stream>>>(Apk, Bpk, x, eps, Bv, outx, outr);
}

// Round 5
// 181.146 us; speedup vs baseline: 1.6624x; 1.0278x over previous
//
#include <hip/hip_runtime.h>
#include <cstdint>
#include <cstddef>

// ---------------------------------------------------------------------------
// ThalamicRNN step. FP32 in/out; internal GEMM bf16 MFMA + fp32 accum.
//   A'  = [ r | stim ]           (2048 x 2176) bf16   (KA = 2176)
//   B'  = [ J^T | I_stim^T | U ] (2048 x 2240) bf16   (KB = 2240)
//   t[b,p] = tha[b,p] * (r @ V^T)[b,p]  -- split-K partials in prep,
//            reduced per-block inside main_gemm as the final K-tile vs U.
//   acc = A'@B'^T (+ t@U^T); x_new = x + (DT/TAU)*(-x+acc+B+SIG*eps);
//   r_new = softplus(x_new)
// Round 5: 2 kernels total. 64x64 main tiles (1024 blocks, 4/CU).
// ---------------------------------------------------------------------------

#define KA 2176
#define KB 2240
#define NN 2048

using frag_ab = __attribute__((ext_vector_type(8))) short;   // 8 bf16
using frag_cd = __attribute__((ext_vector_type(4))) float;   // 4 fp32

__device__ __forceinline__ unsigned short f2bf(float f) {
  union { float f; unsigned int i; } v;
  v.f = f;
  unsigned int r = v.i + 0x7fffu + ((v.i >> 16) & 1u);  // RNE
  return (unsigned short)(r >> 16);
}

__device__ __forceinline__ uint4 cvt8(const float* __restrict__ p) {
  float4 a = *(const float4*)p;
  float4 b = *(const float4*)(p + 4);
  union { uint4 v; unsigned short u[8]; } d;
  d.u[0] = f2bf(a.x); d.u[1] = f2bf(a.y); d.u[2] = f2bf(a.z); d.u[3] = f2bf(a.w);
  d.u[4] = f2bf(b.x); d.u[5] = f2bf(b.y); d.u[6] = f2bf(b.z); d.u[7] = f2bf(b.w);
  return d.v;
}

// async global->LDS, 16 B/lane; LDS dest = wave-uniform base + lane*16.
__device__ __forceinline__ void gl_lds16(const void* g, void* l) {
  __builtin_amdgcn_global_load_lds(
      (const __attribute__((address_space(1))) void*)g,
      (__attribute__((address_space(3))) void*)l, 16, 0, 0);
}

// ---------------------------------------------------------------------------
// prep: blocks [0,1024)  J transpose -> Bp cols [0,2048)
//       [1024,1088)      I_stim transpose -> Bp cols [2048,2176)
//       [1088,3136)      r -> Ap cols [0,2048), stim -> Ap [2048,2176),
//                        U -> Bp cols [2176,2240)
//       [3136,3392)      t split-K partials: part[s][b][p] fp32
// ---------------------------------------------------------------------------
__global__ __launch_bounds__(256) void prep(
    const float* __restrict__ J, const float* __restrict__ Ist,
    const float* __restrict__ rg, const float* __restrict__ stim,
    const float* __restrict__ U, const float* __restrict__ V,
    unsigned short* __restrict__ Ap, unsigned short* __restrict__ Bp,
    float* __restrict__ part) {
  __shared__ unsigned short tile[64 * 66];
  __shared__ alignas(16) unsigned short Ats[32 * 64];
  __shared__ alignas(16) unsigned short Bts[64 * 64];
  const int blk = blockIdx.x;
  const int t = threadIdx.x;

  if (blk < 1088) {                      // ---- transposes ----
    const float* src;
    int dst_off, cx, cy;
    if (blk < 1024) { src = J;   dst_off = 0;    cx = blk & 31; cy = blk >> 5; }
    else            { src = Ist; dst_off = 2048; cx = (blk - 1024) & 31; cy = (blk - 1024) >> 5; }
    const int r0 = cy * 64, c0 = cx * 64;
    const int sr = t >> 3, c8 = t & 7;
#pragma unroll
    for (int p = 0; p < 2; ++p) {
      const int row = sr + 32 * p;
      union { uint4 v; unsigned short u[8]; } d;
      d.v = cvt8(&src[(size_t)(r0 + row) * 2048 + c0 + c8 * 8]);
#pragma unroll
      for (int e = 0; e < 8; ++e) tile[row * 66 + c8 * 8 + e] = d.u[e];
    }
    __syncthreads();
#pragma unroll
    for (int p = 0; p < 2; ++p) {
      const int scol = sr + 32 * p;
      union { uint4 v; unsigned short u[8]; } d;
#pragma unroll
      for (int e = 0; e < 8; ++e) d.u[e] = tile[(c8 * 8 + e) * 66 + scol];
      *(uint4*)&Bp[(size_t)(c0 + scol) * KB + dst_off + r0 + c8 * 8] = d.v;
    }
  } else if (blk < 3136) {               // ---- pack r / stim / U ----
    const int row = blk - 1088;
    *(uint4*)&Ap[(size_t)row * KA + t * 8] = cvt8(&rg[(size_t)row * 2048 + t * 8]);
    if (t < 24) {
      const int c = 256 + t;
      if (c < 272)
        *(uint4*)&Ap[(size_t)row * KA + c * 8] =
            cvt8(&stim[(size_t)row * 128 + (c - 256) * 8]);
      else
        *(uint4*)&Bp[(size_t)row * KB + c * 8] =
            cvt8(&U[(size_t)row * 64 + (c - 272) * 8]);
    }
  } else {                               // ---- t split-K partial GEMM ----
    const int tb = blk - 3136;
    const int mt = tb & 63, s = tb >> 6;
    const int b0 = mt * 32;
    const int wave = t >> 6, lane = t & 63;
    const int q = lane >> 4, l15 = lane & 15;
    const int arow = t >> 3, ac8 = t & 7;

    const float* gA  = rg + (size_t)(b0 + arow) * 2048 + s * 512 + ac8 * 8;
    const float* gB0 = V  + (size_t)arow        * 2048 + s * 512 + ac8 * 8;
    const float* gB1 = V  + (size_t)(arow + 32) * 2048 + s * 512 + ac8 * 8;

    frag_cd acc0 = {0.f, 0.f, 0.f, 0.f};
    frag_cd acc1 = {0.f, 0.f, 0.f, 0.f};

    for (int kt = 0; kt < 8; ++kt) {
      const int k0 = kt * 64;
      uint4 va  = cvt8(gA + k0);
      uint4 vb0 = cvt8(gB0 + k0);
      uint4 vb1 = cvt8(gB1 + k0);
      __syncthreads();
      *(uint4*)&Ats[t * 8]        = va;
      *(uint4*)&Bts[t * 8]        = vb0;
      *(uint4*)&Bts[2048 + t * 8] = vb1;
      __syncthreads();
#pragma unroll
      for (int ks = 0; ks < 2; ++ks) {
        frag_ab a0 = *(const frag_ab*)&Ats[(l15)      * 64 + ks * 32 + q * 8];
        frag_ab a1 = *(const frag_ab*)&Ats[(16 + l15) * 64 + ks * 32 + q * 8];
        frag_ab b  = *(const frag_ab*)&Bts[(wave * 16 + l15) * 64 + ks * 32 + q * 8];
        acc0 = __builtin_amdgcn_mfma_f32_16x16x32_bf16(a0, b, acc0, 0, 0, 0);
        acc1 = __builtin_amdgcn_mfma_f32_16x16x32_bf16(a1, b, acc1, 0, 0, 0);
      }
    }
    const int p = wave * 16 + l15;
#pragma unroll
    for (int reg = 0; reg < 4; ++reg) {
      const int m0 = q * 4 + reg;   // C/D: row = quad*4+reg, col = lane&15
      part[((size_t)s * 2048 + b0 + m0) * 64 + p]      = acc0[reg];
      part[((size_t)s * 2048 + b0 + m0 + 16) * 64 + p] = acc1[reg];
    }
  }
}

// ---------------------------------------------------------------------------
// Main GEMM + fused t-reduce + epilogue. 64x64 tile, BK=64, 256 threads
// (4 waves, each 32x32, acc[2][2]). 34 async-staged K-iters over A'/B',
// then a peeled 35th iter: A-side = t (reduced from part, *tha, ->bf16)
// written straight to LDS; B-side = U tile.
// ---------------------------------------------------------------------------
__global__ __launch_bounds__(256, 4) void main_gemm(
    const unsigned short* __restrict__ Ap, const unsigned short* __restrict__ Bp,
    const float* __restrict__ part, const float* __restrict__ tha,
    const float* __restrict__ xg, const float* __restrict__ epsg,
    const float* __restrict__ Bvec,
    float* __restrict__ outx, float* __restrict__ outr) {
  __shared__ alignas(16) unsigned short As[64 * 64];    // 8 KB
  __shared__ alignas(16) unsigned short Bs[64 * 64];    // 8 KB

  const int t = threadIdx.x;
  const int wave = t >> 6, lane = t & 63;
  const int q = lane >> 4, l15 = lane & 15, l7 = lane & 7;
  const int wm = (wave & 1) * 32, wn = (wave >> 1) * 32;
  const int bm0 = blockIdx.y * 64, bn0 = blockIdx.x * 64;

  // staging slots: slot ci (16B units) holds row=ci>>3, logical chunk (ci&7)^(row&7)
  const unsigned short* gA[2];
  const unsigned short* gB[2];
  unsigned short* lA[2];
  unsigned short* lB[2];
  uint4 tval[2];                 // this thread's two t-tile slots (bf16 x8)
#pragma unroll
  for (int r = 0; r < 2; ++r) {
    const int ci = r * 256 + t;
    const int row = ci >> 3;
    const int lc = (ci & 7) ^ (row & 7);
    gA[r] = Ap + (size_t)(bm0 + row) * KA + lc * 8;
    gB[r] = Bp + (size_t)(bn0 + row) * KB + lc * 8;
    lA[r] = As + (size_t)(r * 256 + wave * 64) * 8;   // wave-uniform base
    lB[r] = Bs + (size_t)(r * 256 + wave * 64) * 8;

    // ---- t-tile: t[bm0+row][p0..p0+8) = tha * sum_s part[s] ----
    const int p0 = lc * 8;
    const size_t base = ((size_t)(bm0 + row)) * 64 + p0;
    float4 s0 = *(const float4*)&part[base];
    float4 s1 = *(const float4*)&part[base + 4];
#pragma unroll
    for (int s = 1; s < 4; ++s) {
      float4 a = *(const float4*)&part[(size_t)s * 131072 + base];
      float4 b = *(const float4*)&part[(size_t)s * 131072 + base + 4];
      s0.x += a.x; s0.y += a.y; s0.z += a.z; s0.w += a.w;
      s1.x += b.x; s1.y += b.y; s1.z += b.z; s1.w += b.w;
    }
    float4 th0 = *(const float4*)&tha[base];
    float4 th1 = *(const float4*)&tha[base + 4];
    union { uint4 v; unsigned short u[8]; } d;
    d.u[0] = f2bf(th0.x * s0.x); d.u[1] = f2bf(th0.y * s0.y);
    d.u[2] = f2bf(th0.z * s0.z); d.u[3] = f2bf(th0.w * s0.w);
    d.u[4] = f2bf(th1.x * s1.x); d.u[5] = f2bf(th1.y * s1.y);
    d.u[6] = f2bf(th1.z * s1.z); d.u[7] = f2bf(th1.w * s1.w);
    tval[r] = d.v;
  }

  frag_cd acc[2][2];
#pragma unroll
  for (int i = 0; i < 2; ++i)
#pragma unroll
    for (int j = 0; j < 2; ++j) {
      frag_cd z = {0.f, 0.f, 0.f, 0.f};
      acc[i][j] = z;
    }

#pragma unroll 1
  for (int kt = 0; kt < 34; ++kt) {  // A' has exactly 34 K-tiles (2176)
    const int k0 = kt * 64;
    __syncthreads();
#pragma unroll
    for (int r = 0; r < 2; ++r) {
      gl_lds16(gA[r] + k0, lA[r]);
      gl_lds16(gB[r] + k0, lB[r]);
    }
    __syncthreads();
#pragma unroll
    for (int ks = 0; ks < 2; ++ks) {
      const int lc = ks * 4 + q;
      frag_ab af[2], bfr[2];
#pragma unroll
      for (int i = 0; i < 2; ++i) {
        af[i]  = *(const frag_ab*)&As[(wm + i * 16 + l15) * 64 + ((lc ^ l7) * 8)];
        bfr[i] = *(const frag_ab*)&Bs[(wn + i * 16 + l15) * 64 + ((lc ^ l7) * 8)];
      }
#pragma unroll
      for (int i = 0; i < 2; ++i)
#pragma unroll
        for (int j = 0; j < 2; ++j)
          acc[i][j] = __builtin_amdgcn_mfma_f32_16x16x32_bf16(af[i], bfr[j], acc[i][j], 0, 0, 0);
    }
  }

  // ---- peeled K-tile 34: A-side = t (from registers), B-side = U ----
  {
    const int k0 = 34 * 64;    // 2176, valid for B' (KB=2240)
    __syncthreads();
#pragma unroll
    for (int r = 0; r < 2; ++r) {
      *(uint4*)&As[(size_t)(r * 256 + t) * 8] = tval[r];
      gl_lds16(gB[r] + k0, lB[r]);
    }
    __syncthreads();
#pragma unroll
    for (int ks = 0; ks < 2; ++ks) {
      const int lc = ks * 4 + q;
      frag_ab af[2], bfr[2];
#pragma unroll
      for (int i = 0; i < 2; ++i) {
        af[i]  = *(const frag_ab*)&As[(wm + i * 16 + l15) * 64 + ((lc ^ l7) * 8)];
        bfr[i] = *(const frag_ab*)&Bs[(wn + i * 16 + l15) * 64 + ((lc ^ l7) * 8)];
      }
#pragma unroll
      for (int i = 0; i < 2; ++i)
#pragma unroll
        for (int j = 0; j < 2; ++j)
          acc[i][j] = __builtin_amdgcn_mfma_f32_16x16x32_bf16(af[i], bfr[j], acc[i][j], 0, 0, 0);
    }
  }

  // ---- epilogue: fp32 direct from accumulator C-layout -------------------
  const float A_DT = 0.33333334f;          // DT/TAU
  const float SIG  = 0.81649658092772615f; // sqrt(2*DT/TAU)
#pragma unroll
  for (int j = 0; j < 2; ++j) {
    const int nc = bn0 + wn + j * 16 + l15;    // C/D col = lane&15
    const float bvf = Bvec[nc];
#pragma unroll
    for (int i = 0; i < 2; ++i) {
#pragma unroll
      for (int reg = 0; reg < 4; ++reg) {
        const int mr = bm0 + wm + i * 16 + q * 4 + reg;  // C/D row = quad*4+reg
        const size_t off = (size_t)mr * NN + nc;
        const float xf = xg[off];
        const float ef = epsg[off];
        const float xn = xf + A_DT * (acc[i][j][reg] + bvf - xf + SIG * ef);
        outx[off] = xn;
        outr[off] = (xn > 20.f) ? xn : log1pf(__expf(xn));
      }
    }
  }
}

// ---------------------------------------------------------------------------
extern "C" void kernel_launch(void* const* d_in, const int* in_sizes, int n_in,
                              void* d_out, int out_size, void* d_ws, size_t ws_size,
                              hipStream_t stream) {
  (void)in_sizes; (void)n_in; (void)out_size; (void)ws_size;
  const float* tha  = (const float*)d_in[0];  // (2048,64)
  const float* stim = (const float*)d_in[1];  // (2048,128)
  const float* x    = (const float*)d_in[2];  // (2048,2048)
  const float* r    = (const float*)d_in[3];  // (2048,2048)
  const float* J    = (const float*)d_in[4];  // (2048,2048)
  const float* Bv   = (const float*)d_in[5];  // (1,2048)
  const float* U    = (const float*)d_in[6];  // (2048,64)
  const float* V    = (const float*)d_in[7];  // (64,2048)
  const float* Ist  = (const float*)d_in[8];  // (128,2048)
  const float* eps  = (const float*)d_in[9];  // (2048,2048)

  unsigned short* Apk = (unsigned short*)d_ws;            // 2048*2176 bf16 (8.5 MB)
  unsigned short* Bpk = Apk + (size_t)NN * KA;            // 2048*2240 bf16 (9.2 MB)
  float* part = (float*)(Bpk + (size_t)NN * KB);          // 4*2048*64 fp32 (2 MB)
  float* outx = (float*)d_out;
  float* outr = outx + (size_t)NN * NN;

  prep<<<3392, 256, 0, stream>>>(J, Ist, r, stim, U, V, Apk, Bpk, part);
  main_gemm<<<dim3(32, 32), 256, 0, stream>>>(Apk, Bpk, part, tha, x, eps, Bv,
                                              outx, outr);
}